// Round 6
// baseline (226.995 us; speedup 1.0000x reference)
//
#include <hip/hip_runtime.h>
#include <hip/hip_bf16.h>
#include <cstdint>

#define BATCH 4096
#define LAT   2048
#define NFREQ 2074
#define KPAD  2112   // NFREQ padded up to a multiple of 64 (zero-filled); 66 K-iters

typedef __bf16 bf16x8 __attribute__((ext_vector_type(8)));
typedef float  f32x4  __attribute__((ext_vector_type(4)));

__device__ __forceinline__ unsigned short f2bf(float f) {
    unsigned int u = __float_as_uint(f);
    u = (u + 0x7fffu + ((u >> 16) & 1u)) >> 16;
    return (unsigned short)u;
}

__device__ __forceinline__ void gload_lds16(const unsigned short* g, unsigned short* l) {
    __builtin_amdgcn_global_load_lds(
        (const __attribute__((address_space(1))) unsigned int*)g,
        (__attribute__((address_space(3))) unsigned int*)l,
        16, 0, 0);
}

// ---------------------------------------------------------------------------
// prep: blocks [0,4096)    -> cast x fp32 -> bf16 (8 elem/thread) + init max
//       blocks [4096,5152) -> transpose+cast W  -> WT  [LAT][KPAD]
//       blocks [5152,6208) -> transpose+cast cb -> cosT[LAT][KPAD]
__global__ void prep_kernel(const float* __restrict__ x,
                            const float* __restrict__ W,
                            const float* __restrict__ cb,
                            unsigned short* __restrict__ xb,
                            unsigned short* __restrict__ WT,
                            unsigned short* __restrict__ cosT,
                            float* __restrict__ maxp) {
    __shared__ float t[64][65];
    const int bid = blockIdx.x;
    const int tid = threadIdx.x;
    if (bid < 4096) {
        int i = bid * 256 + tid;
        const float4* x4 = (const float4*)x;
        float4 a = x4[2 * i];
        float4 b = x4[2 * i + 1];
        union { unsigned short us[8]; uint4 v; } p;
        p.us[0] = f2bf(a.x); p.us[1] = f2bf(a.y); p.us[2] = f2bf(a.z); p.us[3] = f2bf(a.w);
        p.us[4] = f2bf(b.x); p.us[5] = f2bf(b.y); p.us[6] = f2bf(b.z); p.us[7] = f2bf(b.w);
        ((uint4*)xb)[i] = p.v;
        if (i == 0) *maxp = -__builtin_inff();
        return;
    }
    int b2 = bid - 4096;
    const float* in     = (b2 < 1056) ? W  : cb;
    unsigned short* out = (b2 < 1056) ? WT : cosT;
    if (b2 >= 1056) b2 -= 1056;
    const int c0 = (b2 % 32) * 64;
    const int r0 = (b2 / 32) * 64;
    for (int i = tid; i < 4096; i += 256) {
        int rr = i >> 6, cc = i & 63;
        int r = r0 + rr;
        float v = (r < NFREQ) ? in[(size_t)r * LAT + c0 + cc] : 0.0f;
        t[rr][cc] = v;
    }
    __syncthreads();
    for (int i = tid; i < 4096; i += 256) {
        int cc = i >> 6, rr = i & 63;
        out[(size_t)(c0 + cc) * KPAD + (r0 + rr)] = f2bf(t[rr][cc]);
    }
}

// ---------------------------------------------------------------------------
// GEMM1: C[m][n] = sum_k A[m][k]*Bt[n][k], bf16 out.
// 64x64 block tile, 4 waves (2m x 2n of 32x32 wave tiles), BK=32, 3-stage
// circular LDS, one raw s_barrier per iter, vmcnt(2) straddle (each wave
// issues 2 DMAs/iter: 1 A-chunk + 1 B-chunk). Coalesced fetch mapping.
// Grid 1024 = 4 blocks/CU (LDS 24 KB) -> 16 waves/CU (was 8, grid-limited).
template <int N, int K>
__global__ __launch_bounds__(256, 4)
void gemm1_kernel(const unsigned short* __restrict__ A,
                  const unsigned short* __restrict__ Bt,
                  unsigned short* __restrict__ C) {
    __shared__ alignas(16) unsigned short As[3][64 * 32];
    __shared__ alignas(16) unsigned short Bs[3][64 * 32];

    const int tid  = threadIdx.x;
    const int wave = tid >> 6;
    const int lane = tid & 63;
    const int wm   = (wave >> 1) * 32;
    const int wn   = (wave & 1) * 32;
    const int quad = lane >> 4;
    const int l16  = lane & 15;

    const int mBase = blockIdx.y * 64;
    const int nBase = blockIdx.x * 64;

    const int srow = lane >> 2;        // coalesced: 4 lanes cover 64 contig bytes
    const int sk   = (lane & 3) * 8;

    const unsigned short* Ab = A  + (size_t)(mBase + wave * 16 + srow) * K + sk;
    const unsigned short* Bb = Bt + (size_t)(nBase + wave * 16 + srow) * K + sk;
    const int coff = (wave * 16) * 32;

    constexpr int NIT = K / 32;
    gload_lds16(Ab, &As[0][coff]);
    gload_lds16(Bb, &Bs[0][coff]);

    f32x4 acc[2][2] = {};
    int bc = 0;
    for (int j = 0; j < NIT; ++j) {
        const int bn = (bc == 2) ? 0 : bc + 1;
        if (j + 1 < NIT) {
            const int k0 = (j + 1) * 32;
            gload_lds16(Ab + k0, &As[bn][coff]);
            gload_lds16(Bb + k0, &Bs[bn][coff]);
            asm volatile("s_waitcnt vmcnt(2)\n\ts_barrier" ::: "memory");
        } else {
            asm volatile("s_waitcnt vmcnt(0)\n\ts_barrier" ::: "memory");
        }
        bf16x8 af[2], bfr[2];
#pragma unroll
        for (int mi = 0; mi < 2; ++mi)
            af[mi] = *(const bf16x8*)&As[bc][(wm + mi * 16 + l16) * 32 + quad * 8];
#pragma unroll
        for (int ni = 0; ni < 2; ++ni)
            bfr[ni] = *(const bf16x8*)&Bs[bc][(wn + ni * 16 + l16) * 32 + quad * 8];
#pragma unroll
        for (int mi = 0; mi < 2; ++mi)
#pragma unroll
            for (int ni = 0; ni < 2; ++ni)
                acc[mi][ni] = __builtin_amdgcn_mfma_f32_16x16x32_bf16(
                    af[mi], bfr[ni], acc[mi][ni], 0, 0, 0);
        bc = bn;
    }

    // C/D layout: col = lane&15, row = quad*4 + reg
#pragma unroll
    for (int mi = 0; mi < 2; ++mi)
#pragma unroll
        for (int ni = 0; ni < 2; ++ni) {
            int col = nBase + wn + ni * 16 + l16;
#pragma unroll
            for (int r = 0; r < 4; ++r) {
                int row = mBase + wm + mi * 16 + quad * 4 + r;
                C[(size_t)row * N + col] = f2bf(acc[mi][ni][r]);
            }
        }
}

// ---------------------------------------------------------------------------
// GEMM2: out[m][n] = sum_k A[m][k]*Bt[n][k], fp32 out + fused global max.
// 128x64 block tile, 4 waves (2m x 2n of 64x32 wave tiles), BK=32, 3-stage
// circular LDS, vmcnt(3) straddle (each wave: 2 A-chunks + 1 B-chunk per
// iter). Grid 1024 = 4 blocks/CU (LDS 36 KB) -> 16 waves/CU as 4 independent
// blocks (round 5 had the same 16 waves/CU but as 2 blocks: barrier-wide
// stalls coupled 8 waves; finer blocks interleave the drains).
// Max: wave-reduce -> LDS -> ONE atomic per block (1024 total, harmless).
template <int N, int K>
__global__ __launch_bounds__(256, 4)
void gemm2_kernel(const unsigned short* __restrict__ A,
                  const unsigned short* __restrict__ Bt,
                  float* __restrict__ C,
                  float* __restrict__ maxp) {
    __shared__ alignas(16) unsigned short As[3][128 * 32];
    __shared__ alignas(16) unsigned short Bs[3][64 * 32];
    __shared__ float redbuf[4];

    const int tid  = threadIdx.x;
    const int wave = tid >> 6;
    const int lane = tid & 63;
    const int wm   = (wave >> 1) * 64;
    const int wn   = (wave & 1) * 32;
    const int quad = lane >> 4;
    const int l16  = lane & 15;

    const int mBase = blockIdx.y * 128;
    const int nBase = blockIdx.x * 64;

    const int srow = lane >> 2;
    const int sk   = (lane & 3) * 8;

    const unsigned short* Ab1 = A  + (size_t)(mBase + (wave * 2 + 0) * 16 + srow) * K + sk;
    const unsigned short* Ab2 = A  + (size_t)(mBase + (wave * 2 + 1) * 16 + srow) * K + sk;
    const unsigned short* Bb1 = Bt + (size_t)(nBase + wave * 16 + srow) * K + sk;

    const int aoff1 = ((wave * 2 + 0) * 16) * 32;
    const int aoff2 = ((wave * 2 + 1) * 16) * 32;
    const int boff  = (wave * 16) * 32;

    constexpr int NIT = K / 32;
    gload_lds16(Ab1, &As[0][aoff1]);
    gload_lds16(Ab2, &As[0][aoff2]);
    gload_lds16(Bb1, &Bs[0][boff]);

    f32x4 acc[4][2] = {};
    int bc = 0;
    for (int j = 0; j < NIT; ++j) {
        const int bn = (bc == 2) ? 0 : bc + 1;
        if (j + 1 < NIT) {
            const int k0 = (j + 1) * 32;
            gload_lds16(Ab1 + k0, &As[bn][aoff1]);
            gload_lds16(Ab2 + k0, &As[bn][aoff2]);
            gload_lds16(Bb1 + k0, &Bs[bn][boff]);
            asm volatile("s_waitcnt vmcnt(3)\n\ts_barrier" ::: "memory");
        } else {
            asm volatile("s_waitcnt vmcnt(0)\n\ts_barrier" ::: "memory");
        }
        bf16x8 af[4], bfr[2];
#pragma unroll
        for (int mi = 0; mi < 4; ++mi)
            af[mi] = *(const bf16x8*)&As[bc][(wm + mi * 16 + l16) * 32 + quad * 8];
#pragma unroll
        for (int ni = 0; ni < 2; ++ni)
            bfr[ni] = *(const bf16x8*)&Bs[bc][(wn + ni * 16 + l16) * 32 + quad * 8];
#pragma unroll
        for (int mi = 0; mi < 4; ++mi)
#pragma unroll
            for (int ni = 0; ni < 2; ++ni)
                acc[mi][ni] = __builtin_amdgcn_mfma_f32_16x16x32_bf16(
                    af[mi], bfr[ni], acc[mi][ni], 0, 0, 0);
        bc = bn;
    }

    // epilogue: fp32 store + block max + one atomic
    float vmax = -__builtin_inff();
#pragma unroll
    for (int mi = 0; mi < 4; ++mi)
#pragma unroll
        for (int ni = 0; ni < 2; ++ni) {
            int col = nBase + wn + ni * 16 + l16;
#pragma unroll
            for (int r = 0; r < 4; ++r) {
                int row = mBase + wm + mi * 16 + quad * 4 + r;
                float v = acc[mi][ni][r];
                C[(size_t)row * N + col] = v;
                vmax = fmaxf(vmax, v);
            }
        }
#pragma unroll
    for (int off = 32; off > 0; off >>= 1)
        vmax = fmaxf(vmax, __shfl_xor(vmax, off));
    if (lane == 0) redbuf[wave] = vmax;
    __syncthreads();
    if (tid == 0) {
        float m = fmaxf(fmaxf(redbuf[0], redbuf[1]), fmaxf(redbuf[2], redbuf[3]));
        if (m >= 0.0f) atomicMax((int*)maxp, __float_as_int(m));
        else           atomicMin((unsigned int*)maxp, __float_as_uint(m));
    }
}

// ---------------------------------------------------------------------------
__global__ void scale_kernel(float* __restrict__ out, const float* __restrict__ maxp) {
    int i = blockIdx.x * blockDim.x + threadIdx.x;
    float inv = 1.0f / (*maxp);
    float4* o4 = (float4*)out;
    float4 v = o4[i];
    v.x *= inv; v.y *= inv; v.z *= inv; v.w *= inv;
    o4[i] = v;
}

// ---------------------------------------------------------------------------
extern "C" void kernel_launch(void* const* d_in, const int* in_sizes, int n_in,
                              void* d_out, int out_size, void* d_ws, size_t ws_size,
                              hipStream_t stream) {
    const float* x  = (const float*)d_in[0];  // (4096, 2048)
    const float* W  = (const float*)d_in[1];  // (2074, 2048)
    const float* cb = (const float*)d_in[2];  // (2074, 2048)

    char* ws = (char*)d_ws;
    unsigned short* xb   = (unsigned short*)ws;                                   // [4096][2048] bf16
    unsigned short* WT   = (unsigned short*)(ws + (size_t)BATCH * LAT * 2);       // [2048][2112] bf16
    unsigned short* cosT = (unsigned short*)((char*)WT + (size_t)LAT * KPAD * 2);
    unsigned short* C1   = (unsigned short*)((char*)cosT + (size_t)LAT * KPAD * 2); // [2048][2048] bf16
    float*          maxp = (float*)((char*)C1 + (size_t)LAT * LAT * 2);
    float*          out  = (float*)d_out;

    // 1. fused prep: cast x -> bf16 (+init max), transpose+cast W and cos_basis
    prep_kernel<<<4096 + 2 * 1056, 256, 0, stream>>>(x, W, cb, xb, WT, cosT, maxp);

    // 2. C1[l2][l1] = sum_f cosT[l2,f] * WT[l1,f]   (64x64 tiles, 1024 blocks)
    gemm1_kernel<LAT, KPAD>
        <<<dim3(LAT / 64, LAT / 64), 256, 0, stream>>>(cosT, WT, C1);

    // 3. out[b][l2] = sum_l1 xb[b][l1] * C1[l2][l1]  (128x64, 1024 blocks, fused max)
    gemm2_kernel<LAT, LAT>
        <<<dim3(LAT / 64, BATCH / 128), 256, 0, stream>>>(xb, C1, out, maxp);

    // 4. out /= max
    scale_kernel<<<(out_size / 4) / 256, 256, 0, stream>>>(out, maxp);
}

// Round 7
// 203.531 us; speedup vs baseline: 1.1153x; 1.1153x over previous
//
#include <hip/hip_runtime.h>
#include <hip/hip_bf16.h>
#include <cstdint>

#define BATCH 4096
#define LAT   2048
#define NFREQ 2074
#define KPAD  2112   // NFREQ padded to multiple of 96: 3 K-splits x 704 (22 iters)

typedef __bf16 bf16x8 __attribute__((ext_vector_type(8)));
typedef float  f32x4  __attribute__((ext_vector_type(4)));

__device__ __forceinline__ unsigned short f2bf(float f) {
    unsigned int u = __float_as_uint(f);
    u = (u + 0x7fffu + ((u >> 16) & 1u)) >> 16;
    return (unsigned short)u;
}

__device__ __forceinline__ void gload_lds16(const unsigned short* g, unsigned short* l) {
    __builtin_amdgcn_global_load_lds(
        (const __attribute__((address_space(1))) unsigned int*)g,
        (__attribute__((address_space(3))) unsigned int*)l,
        16, 0, 0);
}

// ---------------------------------------------------------------------------
// prep: blocks [0,4096)    -> cast x fp32 -> bf16 (8 elem/thread) + init max
//       blocks [4096,5152) -> transpose+cast W  -> WT  [LAT][KPAD]
//       blocks [5152,6208) -> transpose+cast cb -> cosT[LAT][KPAD]
__global__ void prep_kernel(const float* __restrict__ x,
                            const float* __restrict__ W,
                            const float* __restrict__ cb,
                            unsigned short* __restrict__ xb,
                            unsigned short* __restrict__ WT,
                            unsigned short* __restrict__ cosT,
                            float* __restrict__ maxp) {
    __shared__ float t[64][65];
    const int bid = blockIdx.x;
    const int tid = threadIdx.x;
    if (bid < 4096) {
        int i = bid * 256 + tid;
        const float4* x4 = (const float4*)x;
        float4 a = x4[2 * i];
        float4 b = x4[2 * i + 1];
        union { unsigned short us[8]; uint4 v; } p;
        p.us[0] = f2bf(a.x); p.us[1] = f2bf(a.y); p.us[2] = f2bf(a.z); p.us[3] = f2bf(a.w);
        p.us[4] = f2bf(b.x); p.us[5] = f2bf(b.y); p.us[6] = f2bf(b.z); p.us[7] = f2bf(b.w);
        ((uint4*)xb)[i] = p.v;
        if (i == 0) *maxp = -__builtin_inff();
        return;
    }
    int b2 = bid - 4096;
    const float* in     = (b2 < 1056) ? W  : cb;
    unsigned short* out = (b2 < 1056) ? WT : cosT;
    if (b2 >= 1056) b2 -= 1056;
    const int c0 = (b2 % 32) * 64;
    const int r0 = (b2 / 32) * 64;
    for (int i = tid; i < 4096; i += 256) {
        int rr = i >> 6, cc = i & 63;
        int r = r0 + rr;
        float v = (r < NFREQ) ? in[(size_t)r * LAT + c0 + cc] : 0.0f;
        t[rr][cc] = v;
    }
    __syncthreads();
    for (int i = tid; i < 4096; i += 256) {
        int cc = i >> 6, rr = i & 63;
        out[(size_t)(c0 + cc) * KPAD + (r0 + rr)] = f2bf(t[rr][cc]);
    }
}

// ---------------------------------------------------------------------------
// GEMM1 split-K: Cp[z][m][n] = sum_{k in split z} A[m][k]*Bt[n][k], fp32 out.
// The round-5 WINNING shape: 128x128 block tile, 512 threads = 8 waves
// (2m x 4n of 64x32 wave tiles), BK=32, 3-stage circular LDS, one raw
// s_barrier per iter with vmcnt(2) straddle, coalesced fetch. Split-K=3
// makes the grid 768 = exactly 3 blocks/CU (LDS 48.5 KB allows 3) ->
// 24 waves/CU, probing past round 5's 16. fp32 partials, NO atomics
// (round-4 lesson); a separate combine pass reduces them.
template <int N, int K, int NIT>
__global__ __launch_bounds__(512, 6)
void gemm1_splitk_kernel(const unsigned short* __restrict__ A,
                         const unsigned short* __restrict__ Bt,
                         float* __restrict__ Cp) {
    __shared__ alignas(16) unsigned short As[3][128 * 32];
    __shared__ alignas(16) unsigned short Bs[3][128 * 32];

    const int tid  = threadIdx.x;
    const int wave = tid >> 6;          // 0..7
    const int lane = tid & 63;
    const int wm   = (wave >> 2) * 64;  // m-half
    const int wn   = (wave & 3) * 32;   // n-quarter
    const int quad = lane >> 4;
    const int l16  = lane & 15;

    const int mBase = blockIdx.y * 128;
    const int nBase = blockIdx.x * 128;
    const int kOff  = blockIdx.z * (NIT * 32);
    float* C = Cp + (size_t)blockIdx.z * N * N;

    const int srow = lane >> 2;         // coalesced: 4 lanes = 64 contig bytes
    const int sk   = (lane & 3) * 8;

    const unsigned short* Ab = A  + (size_t)(mBase + wave * 16 + srow) * K + kOff + sk;
    const unsigned short* Bb = Bt + (size_t)(nBase + wave * 16 + srow) * K + kOff + sk;
    const int coff = (wave * 16) * 32;

    gload_lds16(Ab, &As[0][coff]);
    gload_lds16(Bb, &Bs[0][coff]);

    f32x4 acc[4][2] = {};
    int bc = 0;
    for (int j = 0; j < NIT; ++j) {
        const int bn = (bc == 2) ? 0 : bc + 1;
        if (j + 1 < NIT) {
            const int k0 = (j + 1) * 32;
            gload_lds16(Ab + k0, &As[bn][coff]);
            gload_lds16(Bb + k0, &Bs[bn][coff]);
            asm volatile("s_waitcnt vmcnt(2)\n\ts_barrier" ::: "memory");
        } else {
            asm volatile("s_waitcnt vmcnt(0)\n\ts_barrier" ::: "memory");
        }
        bf16x8 af[4], bfr[2];
#pragma unroll
        for (int mi = 0; mi < 4; ++mi)
            af[mi] = *(const bf16x8*)&As[bc][(wm + mi * 16 + l16) * 32 + quad * 8];
#pragma unroll
        for (int ni = 0; ni < 2; ++ni)
            bfr[ni] = *(const bf16x8*)&Bs[bc][(wn + ni * 16 + l16) * 32 + quad * 8];
#pragma unroll
        for (int mi = 0; mi < 4; ++mi)
#pragma unroll
            for (int ni = 0; ni < 2; ++ni)
                acc[mi][ni] = __builtin_amdgcn_mfma_f32_16x16x32_bf16(
                    af[mi], bfr[ni], acc[mi][ni], 0, 0, 0);
        bc = bn;
    }

    // C/D layout: col = lane&15, row = quad*4 + reg; plain fp32 stores
#pragma unroll
    for (int mi = 0; mi < 4; ++mi)
#pragma unroll
        for (int ni = 0; ni < 2; ++ni) {
            int col = nBase + wn + ni * 16 + l16;
#pragma unroll
            for (int r = 0; r < 4; ++r) {
                int row = mBase + wm + mi * 16 + quad * 4 + r;
                C[(size_t)row * N + col] = acc[mi][ni][r];
            }
        }
}

// ---------------------------------------------------------------------------
// combine: C1 = bf16(p0 + p1 + p2), 8 elements/thread
__global__ void combine_kernel(const float* __restrict__ p0,
                               const float* __restrict__ p1,
                               const float* __restrict__ p2,
                               unsigned short* __restrict__ out) {
    int i = blockIdx.x * blockDim.x + threadIdx.x;
    const float4* a4 = (const float4*)p0;
    const float4* b4 = (const float4*)p1;
    const float4* c4 = (const float4*)p2;
    union { unsigned short us[8]; uint4 v; } p;
#pragma unroll
    for (int h = 0; h < 2; ++h) {
        float4 a = a4[2 * i + h], b = b4[2 * i + h], c = c4[2 * i + h];
        p.us[4 * h + 0] = f2bf(a.x + b.x + c.x);
        p.us[4 * h + 1] = f2bf(a.y + b.y + c.y);
        p.us[4 * h + 2] = f2bf(a.z + b.z + c.z);
        p.us[4 * h + 3] = f2bf(a.w + b.w + c.w);
    }
    ((uint4*)out)[i] = p.v;
}

// ---------------------------------------------------------------------------
// GEMM2: round-5 winner, UNCHANGED. out[m][n] = sum_k A[m][k]*Bt[n][k],
// fp32 out + fused global max. 128x128 tile, 512 threads = 8 waves
// (2m x 4n of 64x32 wave tiles), 3-stage circular LDS, vmcnt(2) straddle.
// Max: wave-reduce -> LDS -> ONE atomic per block (512 total).
template <int N, int K>
__global__ __launch_bounds__(512, 4)
void gemm2_kernel(const unsigned short* __restrict__ A,
                  const unsigned short* __restrict__ Bt,
                  float* __restrict__ C,
                  float* __restrict__ maxp) {
    __shared__ alignas(16) unsigned short As[3][128 * 32];
    __shared__ alignas(16) unsigned short Bs[3][128 * 32];
    __shared__ float redbuf[8];

    const int tid  = threadIdx.x;
    const int wave = tid >> 6;          // 0..7
    const int lane = tid & 63;
    const int wm   = (wave >> 2) * 64;  // m-half
    const int wn   = (wave & 3) * 32;   // n-quarter
    const int quad = lane >> 4;
    const int l16  = lane & 15;

    const int mBase = blockIdx.y * 128;
    const int nBase = blockIdx.x * 128;

    const int srow = lane >> 2;
    const int sk   = (lane & 3) * 8;

    const unsigned short* Ab1 = A  + (size_t)(mBase + wave * 16 + srow) * K + sk;
    const unsigned short* Bb1 = Bt + (size_t)(nBase + wave * 16 + srow) * K + sk;
    const int coff = (wave * 16) * 32;

    constexpr int NIT = K / 32;
    gload_lds16(Ab1, &As[0][coff]);
    gload_lds16(Bb1, &Bs[0][coff]);

    f32x4 acc[4][2] = {};
    int bc = 0;
    for (int j = 0; j < NIT; ++j) {
        const int bn = (bc == 2) ? 0 : bc + 1;
        if (j + 1 < NIT) {
            const int k0 = (j + 1) * 32;
            gload_lds16(Ab1 + k0, &As[bn][coff]);
            gload_lds16(Bb1 + k0, &Bs[bn][coff]);
            asm volatile("s_waitcnt vmcnt(2)\n\ts_barrier" ::: "memory");
        } else {
            asm volatile("s_waitcnt vmcnt(0)\n\ts_barrier" ::: "memory");
        }
        bf16x8 af[4], bfr[2];
#pragma unroll
        for (int mi = 0; mi < 4; ++mi)
            af[mi] = *(const bf16x8*)&As[bc][(wm + mi * 16 + l16) * 32 + quad * 8];
#pragma unroll
        for (int ni = 0; ni < 2; ++ni)
            bfr[ni] = *(const bf16x8*)&Bs[bc][(wn + ni * 16 + l16) * 32 + quad * 8];
#pragma unroll
        for (int mi = 0; mi < 4; ++mi)
#pragma unroll
            for (int ni = 0; ni < 2; ++ni)
                acc[mi][ni] = __builtin_amdgcn_mfma_f32_16x16x32_bf16(
                    af[mi], bfr[ni], acc[mi][ni], 0, 0, 0);
        bc = bn;
    }

    // epilogue: fp32 store + block max + one atomic
    float vmax = -__builtin_inff();
#pragma unroll
    for (int mi = 0; mi < 4; ++mi)
#pragma unroll
        for (int ni = 0; ni < 2; ++ni) {
            int col = nBase + wn + ni * 16 + l16;
#pragma unroll
            for (int r = 0; r < 4; ++r) {
                int row = mBase + wm + mi * 16 + quad * 4 + r;
                float v = acc[mi][ni][r];
                C[(size_t)row * N + col] = v;
                vmax = fmaxf(vmax, v);
            }
        }
#pragma unroll
    for (int off = 32; off > 0; off >>= 1)
        vmax = fmaxf(vmax, __shfl_xor(vmax, off));
    if (lane == 0) redbuf[wave] = vmax;
    __syncthreads();
    if (tid == 0) {
        float m = redbuf[0];
#pragma unroll
        for (int w = 1; w < 8; ++w) m = fmaxf(m, redbuf[w]);
        if (m >= 0.0f) atomicMax((int*)maxp, __float_as_int(m));
        else           atomicMin((unsigned int*)maxp, __float_as_uint(m));
    }
}

// ---------------------------------------------------------------------------
__global__ void scale_kernel(float* __restrict__ out, const float* __restrict__ maxp) {
    int i = blockIdx.x * blockDim.x + threadIdx.x;
    float inv = 1.0f / (*maxp);
    float4* o4 = (float4*)out;
    float4 v = o4[i];
    v.x *= inv; v.y *= inv; v.z *= inv; v.w *= inv;
    o4[i] = v;
}

// ---------------------------------------------------------------------------
extern "C" void kernel_launch(void* const* d_in, const int* in_sizes, int n_in,
                              void* d_out, int out_size, void* d_ws, size_t ws_size,
                              hipStream_t stream) {
    const float* x  = (const float*)d_in[0];  // (4096, 2048)
    const float* W  = (const float*)d_in[1];  // (2074, 2048)
    const float* cb = (const float*)d_in[2];  // (2074, 2048)

    char* ws = (char*)d_ws;
    unsigned short* xb   = (unsigned short*)ws;                                   // [4096][2048] bf16
    unsigned short* WT   = (unsigned short*)(ws + (size_t)BATCH * LAT * 2);       // [2048][2112] bf16
    unsigned short* cosT = (unsigned short*)((char*)WT + (size_t)LAT * KPAD * 2);
    unsigned short* C1   = (unsigned short*)((char*)cosT + (size_t)LAT * KPAD * 2); // [2048][2048] bf16
    float*          C1p  = (float*)((char*)C1 + (size_t)LAT * LAT * 2);           // 3x [2048][2048] fp32
    float*          maxp = (float*)((char*)C1p + 3 * (size_t)LAT * LAT * 4);
    float*          out  = (float*)d_out;

    // 1. fused prep: cast x -> bf16 (+init max), transpose+cast W and cos_basis
    prep_kernel<<<4096 + 2 * 1056, 256, 0, stream>>>(x, W, cb, xb, WT, cosT, maxp);

    // 2. split-K=3 GEMM1: C1p[z] = partial (cosT . WT^T), grid 768 = 3 blocks/CU
    gemm1_splitk_kernel<LAT, KPAD, 22>
        <<<dim3(LAT / 128, LAT / 128, 3), 512, 0, stream>>>(cosT, WT, C1p);

    // 3. combine partials -> bf16 C1
    combine_kernel<<<(LAT * LAT / 8) / 256, 256, 0, stream>>>(
        C1p, C1p + (size_t)LAT * LAT, C1p + 2 * (size_t)LAT * LAT, C1);

    // 4. out[b][l2] = sum_l1 xb[b][l1] * C1[l2][l1]  (round-5 winner, unchanged)
    gemm2_kernel<LAT, LAT>
        <<<dim3(LAT / 128, BATCH / 128), 512, 0, stream>>>(xb, C1, out, maxp);

    // 5. out /= max
    scale_kernel<<<(out_size / 4) / 256, 256, 0, stream>>>(out, maxp);
}